// Round 13
// baseline (826.506 us; speedup 1.0000x reference)
//
#include <hip/hip_runtime.h>
#include <hip/hip_bf16.h>
#include <cfloat>

// Problem constants (fixed by the reference setup)
#define NTOT    65536      // B*D*H*W = 4*16*32*32
#define KCODES  1024
#define DM      256
#define SPAT    16384      // D*H*W
#define ZQ_SIZE 16777216   // B*C*D*H*W = 4*256*16384

// d_out layout (floats): [0, ZQ_SIZE) z_q | [ZQ_SIZE] vq_loss | [ZQ_SIZE+1, +65536) indices
// d_out[0..ZQ_SIZE) doubles as scratch for transposed z (zt) until output_kernel.
//
// ws layout (4-byte units)
#define WS_ENORM 0          // 1024 f
#define WS_CSIZE 1024       // 1024 f
#define WS_START 2048       // 1025 i (pad to 1056)
#define WS_LOSSP 3104       // 8192 f
#define WS_HIST  11296      // 256*1024 i
#define WS_SORT  273440     // 65536 i
#define WS_IDX   338976     // 65536 i
#define WS_NEWE  404512     // 262144 f
#define WS_BDIST 666656     // 2*65536 f (split-K partial distances)
#define WS_BIDX  797728     // 2*65536 i (split-K partial indices)

#define GLOAD_LDS16(gp, lp) __builtin_amdgcn_global_load_lds( \
    (const __attribute__((address_space(1))) unsigned int*)(gp), \
    (__attribute__((address_space(3))) unsigned int*)(lp), 16, 0, 0)

__global__ __launch_bounds__(256) void enorm_kernel(const float* __restrict__ embed,
                                                    float* __restrict__ enorm) {
    int k = blockIdx.x;
    int t = threadIdx.x;
    float v = embed[k * DM + t];
    v *= v;
    #pragma unroll
    for (int m = 32; m > 0; m >>= 1) v += __shfl_xor(v, m);
    __shared__ float sm[4];
    if ((t & 63) == 0) sm[t >> 6] = v;
    __syncthreads();
    if (t == 0) enorm[k] = sm[0] + sm[1] + sm[2] + sm[3];
}

// 2048 blocks x 256 threads. Block (n-tile = bx>>1, kh = bx&1): 64 z-rows x 512
// codes (kh half). BM=64, BK=16, k-tile=128 -> 64 stages. Micro-tile 4 rows x 8
// codes (acc 32, proven no-spill @64 VGPR). 24KB LDS x 6 blocks/CU = 144KB ->
// 24 waves/CU: the extra blocks fill each other's barrier/staging gaps.
// zs [c][s] == z global layout -> direct global_load_lds.
// es [128][16] via global_load_lds, granule swizzle g^((r>>1)&3) source AND read
// (proven 2-way-max pattern from r9). T5 setprio around the FMA cluster.
// kh==0 blocks emit the zt transpose during k-tile-0 stages.
// Partials -> bdist/bidx; merge_kernel picks winner (tie -> kh0 = smaller idx).
__global__ __launch_bounds__(256, 6) void argmin_kernel(
    const float* __restrict__ z, const float* __restrict__ embed,
    const float* __restrict__ enorm, float* __restrict__ bdist,
    int* __restrict__ bidx, float* __restrict__ zt) {
    __shared__ __align__(16) float zs[2][16][64];    // [c][s]  4KB each
    __shared__ __align__(16) float es[2][128][16];   // [k][c]  8KB each (swizzled)

    const int tid = threadIdx.x;
    const int bx  = blockIdx.x;
    const int kh  = bx & 1;
    const int n0  = (bx >> 1) * 64;
    const int b   = n0 >> 14;
    const int s0  = n0 & 16383;
    const int ti  = tid >> 4;     // 0..15 -> rows ti*4+u (u<4)
    const int tj  = tid & 15;     // 0..15 -> codes tj + j*16 (j<8, in k-tile)
    const int w   = tid >> 6;     // wave 0..3
    const int l   = tid & 63;     // lane

    // z stage: 16 cols x 64 rows = 4KB; 1 instr/wave (4 cols each).
    auto stage_z = [&](int st, int buf) {
        const int c0 = (st & 15) * 16;
        int cc = c0 + w * 4 + (l >> 4);
        const float* gp = z + (size_t)(b * DM + cc) * SPAT + s0 + (l & 15) * 4;
        GLOAD_LDS16(gp, &zs[buf][w * 4][0]);
    };
    // es stage: 128 rows x 16 c = 8KB; 2 instr/wave (16 rows each). Source
    // pre-swizzled: LDS granule g of row r holds global granule g^((r>>1)&3);
    // r = R + (l>>2) with R%16==0, so (r>>1)&3 == (l>>3)&3.
    auto stage_es = [&](int st, int buf) {
        const int k0 = kh * 512 + (st >> 4) * 128;
        const int c0 = (st & 15) * 16;
        #pragma unroll
        for (int v = 0; v < 2; ++v) {
            int R = w * 32 + v * 16;                 // wave-uniform LDS base row
            int sg = (l & 3) ^ ((l >> 3) & 3);
            const float* gp = embed + (size_t)(k0 + R + (l >> 2)) * DM + c0 + sg * 4;
            GLOAD_LDS16(gp, &es[buf][R][0]);
        }
    };

    stage_z(0, 0);
    stage_es(0, 0);

    float best[4], acc[4][8];
    int   bestk[4];
    #pragma unroll
    for (int i = 0; i < 4; ++i) { best[i] = FLT_MAX; bestk[i] = 0; }

    #pragma unroll 1
    for (int st = 0; st < 64; ++st) {
        const int buf = st & 1;
        const int k0  = kh * 512 + (st >> 4) * 128;

        __syncthreads();   // drains vmcnt(0): staged buf ready; prev readers done

        if (st < 63) { stage_z(st + 1, buf ^ 1); stage_es(st + 1, buf ^ 1); }

        // kh==0, k-tile 0 stages double as the z transpose
        if (kh == 0 && st < 16) {
            const int c0 = st * 16;
            int r = tid >> 2, cg = tid & 3;
            float4 v4;
            v4.x = zs[buf][cg * 4 + 0][r];
            v4.y = zs[buf][cg * 4 + 1][r];
            v4.z = zs[buf][cg * 4 + 2][r];
            v4.w = zs[buf][cg * 4 + 3][r];
            *(float4*)&zt[(size_t)(n0 + r) * DM + c0 + cg * 4] = v4;
        }

        if ((st & 15) == 0) {
            #pragma unroll
            for (int i = 0; i < 4; ++i)
                #pragma unroll
                for (int j = 0; j < 8; ++j) acc[i][j] = 0.f;
        }

        __builtin_amdgcn_s_setprio(1);
        #pragma unroll
        for (int cq = 0; cq < 4; ++cq) {
            float4 zq[4];
            #pragma unroll
            for (int q = 0; q < 4; ++q)
                zq[q] = *(const float4*)&zs[buf][cq * 4 + q][ti * 4];
            const int eoff = ((cq ^ ((tj >> 1) & 3)) << 2);   // j-invariant offset
            #pragma unroll
            for (int j = 0; j < 8; ++j) {
                float4 eb = *(const float4*)&es[buf][tj + j * 16][eoff];
                #pragma unroll
                for (int q = 0; q < 4; ++q) {
                    float ec = (q == 0) ? eb.x : (q == 1) ? eb.y
                             : (q == 2) ? eb.z : eb.w;
                    acc[0][j] = fmaf(zq[q].x, ec, acc[0][j]);
                    acc[1][j] = fmaf(zq[q].y, ec, acc[1][j]);
                    acc[2][j] = fmaf(zq[q].z, ec, acc[2][j]);
                    acc[3][j] = fmaf(zq[q].w, ec, acc[3][j]);
                }
            }
        }
        __builtin_amdgcn_s_setprio(0);

        if ((st & 15) == 15) {   // full 256-c dot done for this k-tile: fold argmin
            #pragma unroll
            for (int j = 0; j < 8; ++j) {
                int q = k0 + tj + j * 16;
                float en = enorm[q];
                #pragma unroll
                for (int i = 0; i < 4; ++i) {
                    float v = fmaf(-2.0f, acc[i][j], en);
                    if (v < best[i]) { best[i] = v; bestk[i] = q; }  // strict <
                }
            }
        }
    }

    // reduce over the 16 tj lanes (contiguous in wave), tie -> smaller k
    #pragma unroll
    for (int i = 0; i < 4; ++i) {
        float bd = best[i];
        int   bk = bestk[i];
        #pragma unroll
        for (int m = 1; m < 16; m <<= 1) {
            float od = __shfl_xor(bd, m);
            int   ok = __shfl_xor(bk, m);
            if (od < bd || (od == bd && ok < bk)) { bd = od; bk = ok; }
        }
        if (tj == 0) {
            int n = n0 + ti * 4 + i;
            bdist[kh * NTOT + n] = bd;
            bidx[kh * NTOT + n]  = bk;
        }
    }
}

// merge split-K halves: exact f32 compare; tie -> kh0 (smaller code index).
__global__ __launch_bounds__(256) void merge_kernel(
    const float* __restrict__ bdist, const int* __restrict__ bidx,
    int* __restrict__ idx, float* __restrict__ dout) {
    int n = blockIdx.x * 256 + threadIdx.x;
    float d0 = bdist[n], d1 = bdist[NTOT + n];
    int k = (d1 < d0) ? bidx[NTOT + n] : bidx[n];
    idx[n] = k;
    dout[ZQ_SIZE + 1 + n] = (float)k;
}

// per-256-row-chunk histogram (LDS atomics only). 256 blocks x 256 thr.
__global__ __launch_bounds__(256) void hist_kernel(const int* __restrict__ idx,
                                                   int* __restrict__ hist) {
    __shared__ int lh[KCODES];
    int ch = blockIdx.x, t = threadIdx.x;
    #pragma unroll
    for (int u = 0; u < 4; ++u) lh[t + u * 256] = 0;
    __syncthreads();
    int k = idx[ch * 256 + t];
    atomicAdd(&lh[k], 1);
    __syncthreads();
    #pragma unroll
    for (int u = 0; u < 4; ++u)
        hist[ch * KCODES + t + u * 256] = lh[t + u * 256];
}

// single block, 1024 threads: per-code prefix over chunks, exclusive scan -> start[],
// fused EMA cluster-size math -> csize[].
__global__ __launch_bounds__(1024) void scan_kernel(
    int* __restrict__ hist, const float* __restrict__ ema_cs,
    int* __restrict__ start, float* __restrict__ csize) {
    int k = threadIdx.x;
    int run = 0;
    for (int ch = 0; ch < 256; ++ch) {
        int t = hist[ch * KCODES + k];
        hist[ch * KCODES + k] = run;
        run += t;
    }
    int lane = k & 63, wv = k >> 6;
    int v = run;
    #pragma unroll
    for (int d = 1; d < 64; d <<= 1) {
        int t = __shfl_up(v, d);
        if (lane >= d) v += t;
    }
    __shared__ int wsum[16];
    if (lane == 63) wsum[wv] = v;
    __syncthreads();
    __shared__ int wpre[16];
    if (k == 0) {
        int s = 0;
        #pragma unroll
        for (int i = 0; i < 16; ++i) { wpre[i] = s; s += wsum[i]; }
    }
    __syncthreads();
    int excl = wpre[wv] + v - run;
    start[k] = excl;
    if (k == 1023) start[1024] = excl + run;
    float ncs = 0.99f * ema_cs[k] + 0.01f * (float)run;
    float r = ncs;
    #pragma unroll
    for (int m = 32; m > 0; m >>= 1) r += __shfl_xor(r, m);
    __shared__ float fs[16];
    if (lane == 0) fs[wv] = r;
    __syncthreads();
    __shared__ float nt;
    if (k == 0) {
        float s = 0.f;
        #pragma unroll
        for (int i = 0; i < 16; ++i) s += fs[i];
        nt = s;
    }
    __syncthreads();
    float n = nt;
    csize[k] = (ncs + 1e-5f) / (n + 1024.0f * 1e-5f) * n;
}

// stable rank within chunk + scatter row id. 256 blocks x 256 thr.
__global__ __launch_bounds__(256) void rank_scatter_kernel(
    const int* __restrict__ idx, const int* __restrict__ hist,
    const int* __restrict__ start, int* __restrict__ sorted) {
    __shared__ int lidx[256];
    int ch = blockIdx.x, t = threadIdx.x;
    int k = idx[ch * 256 + t];
    lidx[t] = k;
    __syncthreads();
    int rank = 0;
    for (int j = 0; j < 255; ++j)
        if (j < t && lidx[j] == k) ++rank;
    sorted[start[k] + hist[ch * KCODES + k] + rank] = ch * 256 + t;
}

// one block per code: coalesced row gather-sum from zt, fused newembed.
__global__ __launch_bounds__(256) void gather_kernel(
    const float* __restrict__ zt, const int* __restrict__ sorted,
    const int* __restrict__ start, const float* __restrict__ ema_es,
    const float* __restrict__ csize, float* __restrict__ newe) {
    int k = blockIdx.x, c = threadIdx.x;
    int s0 = start[k], s1 = start[k + 1];
    float acc = 0.f;
    for (int i = s0; i < s1; ++i) {
        int n = sorted[i];
        acc += zt[(size_t)n * DM + c];
    }
    size_t o = (size_t)k * DM + c;
    newe[o] = (0.99f * ema_es[o] + 0.01f * acc) / csize[k];
}

// z_q gather into (B,C,D,H,W) layout + per-block loss partial.
// 8192 blocks x 256 threads x 8 elements = 16777216. Overwrites zt region.
__global__ __launch_bounds__(256) void output_kernel(
    const float* __restrict__ z, const float* __restrict__ newe,
    const int* __restrict__ idx, float* __restrict__ dout,
    float* __restrict__ lossp) {
    int gid = blockIdx.x * 256 + threadIdx.x;
    float lsum = 0.f;
    #pragma unroll
    for (int it = 0; it < 8; ++it) {
        int o = gid + it * (8192 * 256);
        int s = o & 16383, t2 = o >> 14;
        int c = t2 & 255, b = t2 >> 8;
        int n = (b << 14) + s;
        int k = idx[n];
        float v = newe[(size_t)k * DM + c];
        float zv = z[o];
        dout[o] = v;
        float d = zv - v;
        lsum = fmaf(d, d, lsum);
    }
    #pragma unroll
    for (int m = 32; m > 0; m >>= 1) lsum += __shfl_xor(lsum, m);
    __shared__ float sm[4];
    int t = threadIdx.x;
    if ((t & 63) == 0) sm[t >> 6] = lsum;
    __syncthreads();
    if (t == 0) lossp[blockIdx.x] = sm[0] + sm[1] + sm[2] + sm[3];
}

__global__ __launch_bounds__(256) void loss_final_kernel(const float* __restrict__ lossp,
                                                         float* __restrict__ dout) {
    int t = threadIdx.x;
    float v = 0.f;
    for (int i = t; i < 8192; i += 256) v += lossp[i];
    #pragma unroll
    for (int m = 32; m > 0; m >>= 1) v += __shfl_xor(v, m);
    __shared__ float sm[4];
    if ((t & 63) == 0) sm[t >> 6] = v;
    __syncthreads();
    if (t == 0) dout[ZQ_SIZE] = 0.25f * ((sm[0] + sm[1] + sm[2] + sm[3]) / 16777216.0f);
}

extern "C" void kernel_launch(void* const* d_in, const int* in_sizes, int n_in,
                              void* d_out, int out_size, void* d_ws, size_t ws_size,
                              hipStream_t stream) {
    const float* z      = (const float*)d_in[0];
    const float* embed  = (const float*)d_in[1];
    const float* ema_cs = (const float*)d_in[2];
    const float* ema_es = (const float*)d_in[3];
    float* out = (float*)d_out;
    float* ws  = (float*)d_ws;

    float* enorm = ws + WS_ENORM;
    float* csize = ws + WS_CSIZE;
    int*   start = (int*)(ws + WS_START);
    float* lossp = ws + WS_LOSSP;
    int*   hist  = (int*)(ws + WS_HIST);
    int*   sortd = (int*)(ws + WS_SORT);
    int*   idx   = (int*)(ws + WS_IDX);
    float* newe  = ws + WS_NEWE;
    float* bdist = ws + WS_BDIST;
    int*   bidx  = (int*)(ws + WS_BIDX);
    float* zt    = out;   // d_out[0..ZQ_SIZE) as scratch until output_kernel

    enorm_kernel<<<KCODES, 256, 0, stream>>>(embed, enorm);
    argmin_kernel<<<NTOT / 64 * 2, 256, 0, stream>>>(z, embed, enorm, bdist, bidx, zt);
    merge_kernel<<<NTOT / 256, 256, 0, stream>>>(bdist, bidx, idx, out);
    hist_kernel<<<256, 256, 0, stream>>>(idx, hist);
    scan_kernel<<<1, 1024, 0, stream>>>(hist, ema_cs, start, csize);
    rank_scatter_kernel<<<256, 256, 0, stream>>>(idx, hist, start, sortd);
    gather_kernel<<<KCODES, 256, 0, stream>>>(zt, sortd, start, ema_es, csize, newe);
    output_kernel<<<8192, 256, 0, stream>>>(z, newe, idx, out, lossp);
    loss_final_kernel<<<1, 256, 0, stream>>>(lossp, out);
}

// Round 14
// 624.999 us; speedup vs baseline: 1.3224x; 1.3224x over previous
//
#include <hip/hip_runtime.h>
#include <hip/hip_bf16.h>
#include <cfloat>

// Problem constants (fixed by the reference setup)
#define NTOT    65536      // B*D*H*W = 4*16*32*32
#define KCODES  1024
#define DM      256
#define SPAT    16384      // D*H*W
#define ZQ_SIZE 16777216   // B*C*D*H*W = 4*256*16384

// d_out layout (floats): [0, ZQ_SIZE) z_q | [ZQ_SIZE] vq_loss | [ZQ_SIZE+1, +65536) indices
// d_out[0..ZQ_SIZE) doubles as scratch for transposed z (zt) until output_kernel.
//
// ws layout (4-byte units)
#define WS_ENORM 0          // 1024 f
#define WS_CSIZE 1024       // 1024 f
#define WS_START 2048       // 1025 i (pad to 1056)
#define WS_LOSSP 3104       // 8192 f
#define WS_HIST  11296      // 256*1024 i
#define WS_SORT  273440     // 65536 i
#define WS_IDX   338976     // 65536 i
#define WS_NEWE  404512     // 262144 f
#define WS_BDIST 666656     // 2*65536 f (split-K partial distances)
#define WS_BIDX  797728     // 2*65536 i (split-K partial indices)

#define GLOAD_LDS16(gp, lp) __builtin_amdgcn_global_load_lds( \
    (const __attribute__((address_space(1))) unsigned int*)(gp), \
    (__attribute__((address_space(3))) unsigned int*)(lp), 16, 0, 0)

__global__ __launch_bounds__(256) void enorm_kernel(const float* __restrict__ embed,
                                                    float* __restrict__ enorm) {
    int k = blockIdx.x;
    int t = threadIdx.x;
    float v = embed[k * DM + t];
    v *= v;
    #pragma unroll
    for (int m = 32; m > 0; m >>= 1) v += __shfl_xor(v, m);
    __shared__ float sm[4];
    if ((t & 63) == 0) sm[t >> 6] = v;
    __syncthreads();
    if (t == 0) enorm[k] = sm[0] + sm[1] + sm[2] + sm[3];
}

// 2048 blocks x 256 threads. Block (n-tile = bx>>1, kh = bx&1): 64 z-rows x 512
// codes (kh half). BM=64, BK=16, k-tile=128 -> 64 stages. Micro-tile 4 rows x 8
// codes (acc 32, proven no-spill @64 VGPR with bounds (256,4) -- do NOT raise the
// min-waves bound: (256,6) capped VGPR at 40 and spilled 923MB in r13).
// 24KB LDS -> 6 blocks/CU at runtime (LDS-limited), 24 waves/CU: extra blocks
// fill each other's barrier/staging gaps.
// zs [c][s] == z global layout -> direct global_load_lds.
// es [128][16] via global_load_lds, granule swizzle g^((r>>1)&3) source AND read
// (proven 2-way-max pattern from r9).
// kh==0 blocks emit the zt transpose during k-tile-0 stages.
// Partials -> bdist/bidx; merge_kernel picks winner (tie -> kh0 = smaller idx).
__global__ __launch_bounds__(256, 4) void argmin_kernel(
    const float* __restrict__ z, const float* __restrict__ embed,
    const float* __restrict__ enorm, float* __restrict__ bdist,
    int* __restrict__ bidx, float* __restrict__ zt) {
    __shared__ __align__(16) float zs[2][16][64];    // [c][s]  4KB each
    __shared__ __align__(16) float es[2][128][16];   // [k][c]  8KB each (swizzled)

    const int tid = threadIdx.x;
    const int bx  = blockIdx.x;
    const int kh  = bx & 1;
    const int n0  = (bx >> 1) * 64;
    const int b   = n0 >> 14;
    const int s0  = n0 & 16383;
    const int ti  = tid >> 4;     // 0..15 -> rows ti*4+u (u<4)
    const int tj  = tid & 15;     // 0..15 -> codes tj + j*16 (j<8, in k-tile)
    const int w   = tid >> 6;     // wave 0..3
    const int l   = tid & 63;     // lane

    // z stage: 16 cols x 64 rows = 4KB; 1 instr/wave (4 cols each).
    auto stage_z = [&](int st, int buf) {
        const int c0 = (st & 15) * 16;
        int cc = c0 + w * 4 + (l >> 4);
        const float* gp = z + (size_t)(b * DM + cc) * SPAT + s0 + (l & 15) * 4;
        GLOAD_LDS16(gp, &zs[buf][w * 4][0]);
    };
    // es stage: 128 rows x 16 c = 8KB; 2 instr/wave (16 rows each). Source
    // pre-swizzled: LDS granule g of row r holds global granule g^((r>>1)&3);
    // r = R + (l>>2) with R%16==0, so (r>>1)&3 == (l>>3)&3.
    auto stage_es = [&](int st, int buf) {
        const int k0 = kh * 512 + (st >> 4) * 128;
        const int c0 = (st & 15) * 16;
        #pragma unroll
        for (int v = 0; v < 2; ++v) {
            int R = w * 32 + v * 16;                 // wave-uniform LDS base row
            int sg = (l & 3) ^ ((l >> 3) & 3);
            const float* gp = embed + (size_t)(k0 + R + (l >> 2)) * DM + c0 + sg * 4;
            GLOAD_LDS16(gp, &es[buf][R][0]);
        }
    };

    stage_z(0, 0);
    stage_es(0, 0);

    float best[4], acc[4][8];
    int   bestk[4];
    #pragma unroll
    for (int i = 0; i < 4; ++i) { best[i] = FLT_MAX; bestk[i] = 0; }

    #pragma unroll 1
    for (int st = 0; st < 64; ++st) {
        const int buf = st & 1;
        const int k0  = kh * 512 + (st >> 4) * 128;

        __syncthreads();   // drains vmcnt(0): staged buf ready; prev readers done

        if (st < 63) { stage_z(st + 1, buf ^ 1); stage_es(st + 1, buf ^ 1); }

        // kh==0, k-tile 0 stages double as the z transpose
        if (kh == 0 && st < 16) {
            const int c0 = st * 16;
            int r = tid >> 2, cg = tid & 3;
            float4 v4;
            v4.x = zs[buf][cg * 4 + 0][r];
            v4.y = zs[buf][cg * 4 + 1][r];
            v4.z = zs[buf][cg * 4 + 2][r];
            v4.w = zs[buf][cg * 4 + 3][r];
            *(float4*)&zt[(size_t)(n0 + r) * DM + c0 + cg * 4] = v4;
        }

        if ((st & 15) == 0) {
            #pragma unroll
            for (int i = 0; i < 4; ++i)
                #pragma unroll
                for (int j = 0; j < 8; ++j) acc[i][j] = 0.f;
        }

        #pragma unroll
        for (int cq = 0; cq < 4; ++cq) {
            float4 zq[4];
            #pragma unroll
            for (int q = 0; q < 4; ++q)
                zq[q] = *(const float4*)&zs[buf][cq * 4 + q][ti * 4];
            const int eoff = ((cq ^ ((tj >> 1) & 3)) << 2);   // j-invariant offset
            #pragma unroll
            for (int j = 0; j < 8; ++j) {
                float4 eb = *(const float4*)&es[buf][tj + j * 16][eoff];
                #pragma unroll
                for (int q = 0; q < 4; ++q) {
                    float ec = (q == 0) ? eb.x : (q == 1) ? eb.y
                             : (q == 2) ? eb.z : eb.w;
                    acc[0][j] = fmaf(zq[q].x, ec, acc[0][j]);
                    acc[1][j] = fmaf(zq[q].y, ec, acc[1][j]);
                    acc[2][j] = fmaf(zq[q].z, ec, acc[2][j]);
                    acc[3][j] = fmaf(zq[q].w, ec, acc[3][j]);
                }
            }
        }

        if ((st & 15) == 15) {   // full 256-c dot done for this k-tile: fold argmin
            #pragma unroll
            for (int j = 0; j < 8; ++j) {
                int q = k0 + tj + j * 16;
                float en = enorm[q];
                #pragma unroll
                for (int i = 0; i < 4; ++i) {
                    float v = fmaf(-2.0f, acc[i][j], en);
                    if (v < best[i]) { best[i] = v; bestk[i] = q; }  // strict <
                }
            }
        }
    }

    // reduce over the 16 tj lanes (contiguous in wave), tie -> smaller k
    #pragma unroll
    for (int i = 0; i < 4; ++i) {
        float bd = best[i];
        int   bk = bestk[i];
        #pragma unroll
        for (int m = 1; m < 16; m <<= 1) {
            float od = __shfl_xor(bd, m);
            int   ok = __shfl_xor(bk, m);
            if (od < bd || (od == bd && ok < bk)) { bd = od; bk = ok; }
        }
        if (tj == 0) {
            int n = n0 + ti * 4 + i;
            bdist[kh * NTOT + n] = bd;
            bidx[kh * NTOT + n]  = bk;
        }
    }
}

// merge split-K halves: exact f32 compare; tie -> kh0 (smaller code index).
__global__ __launch_bounds__(256) void merge_kernel(
    const float* __restrict__ bdist, const int* __restrict__ bidx,
    int* __restrict__ idx, float* __restrict__ dout) {
    int n = blockIdx.x * 256 + threadIdx.x;
    float d0 = bdist[n], d1 = bdist[NTOT + n];
    int k = (d1 < d0) ? bidx[NTOT + n] : bidx[n];
    idx[n] = k;
    dout[ZQ_SIZE + 1 + n] = (float)k;
}

// per-256-row-chunk histogram (LDS atomics only). 256 blocks x 256 thr.
__global__ __launch_bounds__(256) void hist_kernel(const int* __restrict__ idx,
                                                   int* __restrict__ hist) {
    __shared__ int lh[KCODES];
    int ch = blockIdx.x, t = threadIdx.x;
    #pragma unroll
    for (int u = 0; u < 4; ++u) lh[t + u * 256] = 0;
    __syncthreads();
    int k = idx[ch * 256 + t];
    atomicAdd(&lh[k], 1);
    __syncthreads();
    #pragma unroll
    for (int u = 0; u < 4; ++u)
        hist[ch * KCODES + t + u * 256] = lh[t + u * 256];
}

// single block, 1024 threads: per-code prefix over chunks, exclusive scan -> start[],
// fused EMA cluster-size math -> csize[].
__global__ __launch_bounds__(1024) void scan_kernel(
    int* __restrict__ hist, const float* __restrict__ ema_cs,
    int* __restrict__ start, float* __restrict__ csize) {
    int k = threadIdx.x;
    int run = 0;
    for (int ch = 0; ch < 256; ++ch) {
        int t = hist[ch * KCODES + k];
        hist[ch * KCODES + k] = run;
        run += t;
    }
    int lane = k & 63, wv = k >> 6;
    int v = run;
    #pragma unroll
    for (int d = 1; d < 64; d <<= 1) {
        int t = __shfl_up(v, d);
        if (lane >= d) v += t;
    }
    __shared__ int wsum[16];
    if (lane == 63) wsum[wv] = v;
    __syncthreads();
    __shared__ int wpre[16];
    if (k == 0) {
        int s = 0;
        #pragma unroll
        for (int i = 0; i < 16; ++i) { wpre[i] = s; s += wsum[i]; }
    }
    __syncthreads();
    int excl = wpre[wv] + v - run;
    start[k] = excl;
    if (k == 1023) start[1024] = excl + run;
    float ncs = 0.99f * ema_cs[k] + 0.01f * (float)run;
    float r = ncs;
    #pragma unroll
    for (int m = 32; m > 0; m >>= 1) r += __shfl_xor(r, m);
    __shared__ float fs[16];
    if (lane == 0) fs[wv] = r;
    __syncthreads();
    __shared__ float nt;
    if (k == 0) {
        float s = 0.f;
        #pragma unroll
        for (int i = 0; i < 16; ++i) s += fs[i];
        nt = s;
    }
    __syncthreads();
    float n = nt;
    csize[k] = (ncs + 1e-5f) / (n + 1024.0f * 1e-5f) * n;
}

// stable rank within chunk + scatter row id. 256 blocks x 256 thr.
__global__ __launch_bounds__(256) void rank_scatter_kernel(
    const int* __restrict__ idx, const int* __restrict__ hist,
    const int* __restrict__ start, int* __restrict__ sorted) {
    __shared__ int lidx[256];
    int ch = blockIdx.x, t = threadIdx.x;
    int k = idx[ch * 256 + t];
    lidx[t] = k;
    __syncthreads();
    int rank = 0;
    for (int j = 0; j < 255; ++j)
        if (j < t && lidx[j] == k) ++rank;
    sorted[start[k] + hist[ch * KCODES + k] + rank] = ch * 256 + t;
}

// one block per code: coalesced row gather-sum from zt, fused newembed.
__global__ __launch_bounds__(256) void gather_kernel(
    const float* __restrict__ zt, const int* __restrict__ sorted,
    const int* __restrict__ start, const float* __restrict__ ema_es,
    const float* __restrict__ csize, float* __restrict__ newe) {
    int k = blockIdx.x, c = threadIdx.x;
    int s0 = start[k], s1 = start[k + 1];
    float acc = 0.f;
    for (int i = s0; i < s1; ++i) {
        int n = sorted[i];
        acc += zt[(size_t)n * DM + c];
    }
    size_t o = (size_t)k * DM + c;
    newe[o] = (0.99f * ema_es[o] + 0.01f * acc) / csize[k];
}

// z_q gather into (B,C,D,H,W) layout + per-block loss partial.
// 8192 blocks x 256 threads x 8 elements = 16777216. Overwrites zt region.
__global__ __launch_bounds__(256) void output_kernel(
    const float* __restrict__ z, const float* __restrict__ newe,
    const int* __restrict__ idx, float* __restrict__ dout,
    float* __restrict__ lossp) {
    int gid = blockIdx.x * 256 + threadIdx.x;
    float lsum = 0.f;
    #pragma unroll
    for (int it = 0; it < 8; ++it) {
        int o = gid + it * (8192 * 256);
        int s = o & 16383, t2 = o >> 14;
        int c = t2 & 255, b = t2 >> 8;
        int n = (b << 14) + s;
        int k = idx[n];
        float v = newe[(size_t)k * DM + c];
        float zv = z[o];
        dout[o] = v;
        float d = zv - v;
        lsum = fmaf(d, d, lsum);
    }
    #pragma unroll
    for (int m = 32; m > 0; m >>= 1) lsum += __shfl_xor(lsum, m);
    __shared__ float sm[4];
    int t = threadIdx.x;
    if ((t & 63) == 0) sm[t >> 6] = lsum;
    __syncthreads();
    if (t == 0) lossp[blockIdx.x] = sm[0] + sm[1] + sm[2] + sm[3];
}

__global__ __launch_bounds__(256) void loss_final_kernel(const float* __restrict__ lossp,
                                                         float* __restrict__ dout) {
    int t = threadIdx.x;
    float v = 0.f;
    for (int i = t; i < 8192; i += 256) v += lossp[i];
    #pragma unroll
    for (int m = 32; m > 0; m >>= 1) v += __shfl_xor(v, m);
    __shared__ float sm[4];
    if ((t & 63) == 0) sm[t >> 6] = v;
    __syncthreads();
    if (t == 0) dout[ZQ_SIZE] = 0.25f * ((sm[0] + sm[1] + sm[2] + sm[3]) / 16777216.0f);
}

extern "C" void kernel_launch(void* const* d_in, const int* in_sizes, int n_in,
                              void* d_out, int out_size, void* d_ws, size_t ws_size,
                              hipStream_t stream) {
    const float* z      = (const float*)d_in[0];
    const float* embed  = (const float*)d_in[1];
    const float* ema_cs = (const float*)d_in[2];
    const float* ema_es = (const float*)d_in[3];
    float* out = (float*)d_out;
    float* ws  = (float*)d_ws;

    float* enorm = ws + WS_ENORM;
    float* csize = ws + WS_CSIZE;
    int*   start = (int*)(ws + WS_START);
    float* lossp = ws + WS_LOSSP;
    int*   hist  = (int*)(ws + WS_HIST);
    int*   sortd = (int*)(ws + WS_SORT);
    int*   idx   = (int*)(ws + WS_IDX);
    float* newe  = ws + WS_NEWE;
    float* bdist = ws + WS_BDIST;
    int*   bidx  = (int*)(ws + WS_BIDX);
    float* zt    = out;   // d_out[0..ZQ_SIZE) as scratch until output_kernel

    enorm_kernel<<<KCODES, 256, 0, stream>>>(embed, enorm);
    argmin_kernel<<<NTOT / 64 * 2, 256, 0, stream>>>(z, embed, enorm, bdist, bidx, zt);
    merge_kernel<<<NTOT / 256, 256, 0, stream>>>(bdist, bidx, idx, out);
    hist_kernel<<<256, 256, 0, stream>>>(idx, hist);
    scan_kernel<<<1, 1024, 0, stream>>>(hist, ema_cs, start, csize);
    rank_scatter_kernel<<<256, 256, 0, stream>>>(idx, hist, start, sortd);
    gather_kernel<<<KCODES, 256, 0, stream>>>(zt, sortd, start, ema_es, csize, newe);
    output_kernel<<<8192, 256, 0, stream>>>(z, newe, idx, out, lossp);
    loss_final_kernel<<<1, 256, 0, stream>>>(lossp, out);
}